// Round 6
// baseline (349.984 us; speedup 1.0000x reference)
//
#include <hip/hip_runtime.h>
#include <hip/hip_bf16.h>

// Shapes: B=2, H=W=64, HW=4096, DIM=32, HID=128
#define HWSZ 4096

typedef _Float16 half8 __attribute__((ext_vector_type(8)));
typedef _Float16 half4 __attribute__((ext_vector_type(4)));
typedef float f32x4 __attribute__((ext_vector_type(4)));

__device__ __forceinline__ float gelu_f(float v) {
    return 0.5f * v * (1.0f + erff(v * 0.7071067811865475f));
}

// ---------------- K1: x(B,HW,32) @ w1(32,128) + b1, gelu -> CL f16 (B,HW,128)
__global__ __launch_bounds__(256) void k1_cl(const float* __restrict__ x,
                                             const float* __restrict__ w1,
                                             const float* __restrict__ b1,
                                             _Float16* __restrict__ xicl) {
    int idx = blockIdx.x * 256 + threadIdx.x;  // (b,p,c)
    int c = idx & 127;
    int p = (idx >> 7) & 4095;
    int b = idx >> 19;
    const float* xr = x + (size_t)(b * HWSZ + p) * 32;
    float acc = b1[c];
#pragma unroll
    for (int k = 0; k < 32; ++k) acc = fmaf(xr[k], w1[k * 128 + c], acc);
    xicl[idx] = (_Float16)gelu_f(acc);
}

// ---------------- dwt transform: dww (128,1,3,3) f32 -> (9,128) f16
__global__ __launch_bounds__(256) void dwtk(const float* __restrict__ dww,
                                            _Float16* __restrict__ dwt) {
    int idx = blockIdx.x * 256 + threadIdx.x;
    if (idx >= 9 * 128) return;
    int c = idx & 127, j = idx >> 7;
    dwt[j * 128 + c] = (_Float16)dww[c * 9 + j];
}

// ---------------- pwt cast: pww (256,128) f32 -> f16 same layout
__global__ __launch_bounds__(256) void pcast(const float* __restrict__ pww,
                                             _Float16* __restrict__ pwt) {
    int idx = blockIdx.x * 256 + threadIdx.x;  // 32768
    pwt[idx] = (_Float16)pww[idx];
}

// ---------------- K2: depthwise 3x3 (pad 1) + bias, CL f16 in/out
__global__ __launch_bounds__(256) void k2_cl(const _Float16* __restrict__ xicl,
                                             const _Float16* __restrict__ dwt,
                                             const float* __restrict__ dwb,
                                             _Float16* __restrict__ dcl) {
    int idx = blockIdx.x * 256 + threadIdx.x;  // (b,p,cg)
    int cg = idx & 15;
    int p = (idx >> 4) & 4095;
    int b = idx >> 16;
    int h = p >> 6, w = p & 63;
    const _Float16* base = xicl + (size_t)b * HWSZ * 128;
    float acc[8];
#pragma unroll
    for (int j = 0; j < 8; ++j) acc[j] = 0.f;
#pragma unroll
    for (int i = 0; i < 3; ++i) {
        int y = h + i - 1;
        if ((unsigned)y > 63u) continue;
#pragma unroll
        for (int j2 = 0; j2 < 3; ++j2) {
            int xx = w + j2 - 1;
            if ((unsigned)xx > 63u) continue;
            half8 v = *(const half8*)(base + ((size_t)(y * 64 + xx)) * 128 + cg * 8);
            half8 wv8 = *(const half8*)(dwt + (i * 3 + j2) * 128 + cg * 8);
#pragma unroll
            for (int j = 0; j < 8; ++j) acc[j] = fmaf((float)v[j], (float)wv8[j], acc[j]);
        }
    }
    half8 o;
#pragma unroll
    for (int j = 0; j < 8; ++j) o[j] = (_Float16)(acc[j] + dwb[cg * 8 + j]);
    *(half8*)(dcl + ((size_t)(b * HWSZ) + p) * 128 + cg * 8) = o;
}

// ---------------- K3G: pointwise 128->256 MFMA GEMM + bias + gelu
__global__ __launch_bounds__(512) void k3G(const _Float16* __restrict__ dcl,
                                           const _Float16* __restrict__ pwt,
                                           const float* __restrict__ pwb,
                                           _Float16* __restrict__ clA,
                                           _Float16* __restrict__ gcl) {
    int tid = threadIdx.x;
    int wv = tid >> 6;
    int l = tid & 63;
    int col = l & 15, kg = l >> 4;
    int blk = blockIdx.x;
    int hf = blockIdx.y;  // 0:a 1:g
    int b = blk >> 8;
    int px0 = (blk & 255) << 4;
    int p = px0 + col;
    const _Float16* bp = dcl + ((size_t)(b * HWSZ) + p) * 128 + kg * 8;
    int oc0 = hf * 128 + wv * 16;
    const _Float16* ap = pwt + (size_t)(oc0 + col) * 128 + kg * 8;
    f32x4 acc = (f32x4){0.f, 0.f, 0.f, 0.f};
#pragma unroll
    for (int cc = 0; cc < 4; ++cc) {
        half8 bf = *(const half8*)(bp + cc * 32);
        half8 af = *(const half8*)(ap + cc * 32);
        acc = __builtin_amdgcn_mfma_f32_16x16x32_f16(af, bf, acc, 0, 0, 0);
    }
    int h = p >> 6, w = p & 63;
    half4 t4;
#pragma unroll
    for (int r = 0; r < 4; ++r) {
        int oc = oc0 + kg * 4 + r;
        t4[r] = (_Float16)gelu_f(acc[r] + pwb[oc]);
    }
    if (hf == 0) {
        _Float16* dst = clA + (size_t)b * 70 * 72 * 128 +
                        ((size_t)(h + 3) * 72 + (w + 3)) * 128 + wv * 16 + kg * 4;
        *(half4*)dst = t4;
    } else {
        *(half4*)(gcl + ((size_t)(b * HWSZ) + p) * 128 + wv * 16 + kg * 4) = t4;
    }
}

// ---------------- zero a channels-last padded buffer (as uints)
__global__ __launch_bounds__(256) void zcl(unsigned int* __restrict__ p) {
    p[blockIdx.x * 256 + threadIdx.x] = 0u;
}

// ---------------- weight transform: (O,128,T) f32 -> (T,Op,128) f16, scaled, zero-pad rows
__global__ __launch_bounds__(256) void wtr(const float* __restrict__ w,
                                           _Float16* __restrict__ o,
                                           int T, int Op, int O, float scale) {
    int idx = blockIdx.x * 256 + threadIdx.x;  // (t, op, c)
    int c = idx & 127;
    int op = (idx >> 7) % Op;
    int t = idx / (128 * Op);
    float v = (op < O) ? w[((size_t)(op * 128 + c)) * T + t] * scale : 0.f;
    o[idx] = (_Float16)v;
}

// ---------------- K4Gv3: offset conv = implicit-im2col MFMA GEMM with LDS-staged B
template <int KK, int PAD, int T, int MT, int NG, int NA, int WPX>
__global__ __launch_bounds__(512) void k4Gv3(const _Float16* __restrict__ cl,
                                             const _Float16* __restrict__ wA,
                                             const float* __restrict__ obias,
                                             float* __restrict__ offb, int OC) {
    constexpr int OCp = MT * 16;
    constexpr int COLS = WPX + KK - 1;
    constexpr int NB = 64 / WPX;  // w0 positions per row
    __shared__ _Float16 bS[KK * COLS * 128];

    int tid = threadIdx.x;
    int blk = blockIdx.x;
    int w0 = (blk % NB) * WPX;
    int h = (blk / NB) & 63;
    int b = blk / (NB * 64);
    const _Float16* clb = cl + (size_t)b * 70 * 72 * 128;

    int hh0 = h + (3 - PAD);
    int ww0 = w0 + (3 - PAD);
    for (int g = tid; g < KK * COLS * 16; g += 512) {
        int r = g / (COLS * 16);
        int rest = g - r * (COLS * 16);
        int c = rest >> 4;
        int s = rest & 15;
        half8 v = *(const half8*)(clb + ((size_t)(hh0 + r) * 72 + (ww0 + c)) * 128 + s * 8);
        *(half8*)&bS[((r * COLS + c) * 16 + (s ^ (c & 7))) * 8] = v;
    }

    int wv = tid >> 6;
    int l = tid & 63;
    int col = l & 15, kg = l >> 4;
    int m = wv % MT;
    int ng = wv / MT;

    const _Float16* apbase = wA + ((size_t)(m * 16 + col)) * 128 + kg * 8;
    half8 afv[4];
#pragma unroll
    for (int cc = 0; cc < 4; ++cc) afv[cc] = *(const half8*)(apbase + cc * 32);

    f32x4 acc[NA];
#pragma unroll
    for (int a = 0; a < NA; ++a) acc[a] = (f32x4){0.f, 0.f, 0.f, 0.f};

    __syncthreads();

    for (int t = 0; t < T; ++t) {
        int ky = t / KK, kx = t - ky * KK;
        half8 afn[4];
        if (t + 1 < T) {
            const _Float16* apn = apbase + (size_t)(t + 1) * OCp * 128;
#pragma unroll
            for (int cc = 0; cc < 4; ++cc) afn[cc] = *(const half8*)(apn + cc * 32);
        }
#pragma unroll
        for (int a = 0; a < NA; ++a) {
            int cw = ng * NA * 16 + a * 16 + col + kx;
#pragma unroll
            for (int cc = 0; cc < 4; ++cc) {
                half8 bf = *(const half8*)&bS[((ky * COLS + cw) * 16 + ((cc * 4 + kg) ^ (cw & 7))) * 8];
                acc[a] = __builtin_amdgcn_mfma_f32_16x16x32_f16(afv[cc], bf, acc[a], 0, 0, 0);
            }
        }
#pragma unroll
        for (int cc = 0; cc < 4; ++cc) afv[cc] = afn[cc];
    }

#pragma unroll
    for (int a = 0; a < NA; ++a) {
        int px = h * 64 + w0 + ng * NA * 16 + a * 16 + col;
#pragma unroll
        for (int r = 0; r < 4; ++r) {
            int oc = m * 16 + kg * 4 + r;
            float v = acc[a][r] * (1.0f / 256.0f) + (oc < OC ? obias[oc] : 0.f);
            offb[((size_t)(b * OCp + oc)) * HWSZ + px] = v;
        }
    }
}

// ---------------- K5Gv4: deformable conv, per-tap pipeline, raw barriers (no vmcnt drain)
// MODE 0: write CL f16 padded interior. MODE 2: write CL f16 flat (B,HW,128).
template <int KK, int PAD, int T, int MODE>
__global__ __launch_bounds__(512, 2) void k5Gv4(const _Float16* __restrict__ cl,
                                                const float* __restrict__ offb, int OFFP,
                                                const _Float16* __restrict__ wM,
                                                const float* __restrict__ bias,
                                                _Float16* __restrict__ outH) {
    __shared__ float4 pwS[T * 16];          // bilinear weights (f32, bit-identical numerics)
    __shared__ uchar4 poS[T * 16];          // cy0, cy1, cx0, cx1 (halo +3 applied)
    __shared__ _Float16 panel[2][16][128];  // double-buffered sampled B panel

    int tid = threadIdx.x;
    int blk = blockIdx.x;
    int b = blk >> 8;
    int px0 = (blk & 255) << 4;
    const _Float16* clb = cl + (size_t)b * 70 * 72 * 128;
    const float* ob = offb + (size_t)b * OFFP * HWSZ;

    // ---- precompute all bilinear params for 16 px x T taps
    for (int q = tid; q < T * 16; q += 512) {
        int t = q >> 4, i = q & 15;
        int p = px0 + i, h = p >> 6, w = p & 63;
        int ky = t / KK, kx = t % KK;
        float dy = ob[(size_t)(2 * t) * HWSZ + p];
        float dx = ob[(size_t)(2 * t + 1) * HWSZ + p];
        float py = (float)(h + ky - PAD) + dy;
        float pxs = (float)(w + kx - PAD) + dx;
        float y0f = floorf(py), x0f = floorf(pxs);
        float wy = py - y0f, wx = pxs - x0f;
        int y0 = (int)y0f, x0 = (int)x0f;
        int y1 = y0 + 1, x1 = x0 + 1;
        bool vy0 = (y0 >= 0) && (y0 < 64), vy1 = (y1 >= 0) && (y1 < 64);
        bool vx0 = (x0 >= 0) && (x0 < 64), vx1 = (x1 >= 0) && (x1 < 64);
        int cy0 = min(max(y0, 0), 63) + 3, cy1 = min(max(y1, 0), 63) + 3;
        int cx0 = min(max(x0, 0), 63) + 3, cx1 = min(max(x1, 0), 63) + 3;
        float w00 = (vy0 && vx0) ? (1.f - wy) * (1.f - wx) : 0.f;
        float w01 = (vy0 && vx1) ? (1.f - wy) * wx : 0.f;
        float w10 = (vy1 && vx0) ? wy * (1.f - wx) : 0.f;
        float w11 = (vy1 && vx1) ? wy * wx : 0.f;
        pwS[q] = make_float4(w00, w01, w10, w11);
        poS[q] = make_uchar4((unsigned char)cy0, (unsigned char)cy1,
                             (unsigned char)cx0, (unsigned char)cx1);
    }
    __syncthreads();

    int sub2 = tid & 31;   // 4-channel slice (half4)
    int i_s = tid >> 5;    // sampling pixel 0..15
    int wv = tid >> 6;     // MFMA wave -> M-tile
    int l = tid & 63;
    int col = l & 15, kg = l >> 4;
    f32x4 acc = (f32x4){0.f, 0.f, 0.f, 0.f};

    half4 cA[4], cB[4];
    half8 wA[4], wB[4];

    auto LOADC = [&](half4* c, int t) {
        if (t >= T) return;
        uchar4 pk = poS[t * 16 + i_s];
        int r0 = ((int)pk.x * 72) << 7;
        int r1 = ((int)pk.y * 72) << 7;
        int q0 = ((int)pk.z) << 7;
        int q1 = ((int)pk.w) << 7;
        const _Float16* s = clb + sub2 * 4;
        c[0] = *(const half4*)(s + r0 + q0);
        c[1] = *(const half4*)(s + r0 + q1);
        c[2] = *(const half4*)(s + r1 + q0);
        c[3] = *(const half4*)(s + r1 + q1);
    };
    auto BW = [&](half4* c, int t) {
        if (t >= T) return;
        float4 wq = pwS[t * 16 + i_s];
        half4 r;
#pragma unroll
        for (int j = 0; j < 4; ++j) {
            float v = wq.x * (float)c[0][j] + wq.y * (float)c[1][j] +
                      wq.z * (float)c[2][j] + wq.w * (float)c[3][j];
            r[j] = (_Float16)v;
        }
        *(half4*)&panel[t & 1][i_s][((sub2 >> 1) ^ (i_s & 7)) * 8 + (sub2 & 1) * 4] = r;
    };
    auto LOADW = [&](half8* w8, int t) {
        if (t >= T) return;
        const _Float16* ap = wM + ((size_t)t * 128 + wv * 16 + col) * 128 + kg * 8;
#pragma unroll
        for (int cc = 0; cc < 4; ++cc) w8[cc] = *(const half8*)(ap + cc * 32);
    };
    auto MM = [&](half8* w8, int t) {
#pragma unroll
        for (int cc = 0; cc < 4; ++cc) {
            half8 bf = *(const half8*)&panel[t & 1][col][((cc * 4 + kg) ^ (col & 7)) * 8];
            acc = __builtin_amdgcn_mfma_f32_16x16x32_f16(w8[cc], bf, acc, 0, 0, 0);
        }
    };
    auto BAR = [&]() {
        asm volatile("s_waitcnt lgkmcnt(0)" ::: "memory");
        __builtin_amdgcn_s_barrier();
        __builtin_amdgcn_sched_barrier(0);
    };

    // prologue
    LOADC(cA, 0);
    LOADC(cB, 1);
    LOADW(wA, 0);
    LOADW(wB, 1);
    BW(cA, 0);
    BAR();

    for (int t = 0; t < T; t += 2) {
        LOADC(cA, t + 2);
        MM(wA, t);
        LOADW(wA, t + 2);
        BW(cB, t + 1);
        BAR();
        if (t + 1 < T) {
            LOADC(cB, t + 3);
            MM(wB, t + 1);
            LOADW(wB, t + 3);
            BW(cA, t + 2);
            BAR();
        }
    }

    int p = px0 + col, h = p >> 6, w = p & 63;
    half4 t4;
#pragma unroll
    for (int r = 0; r < 4; ++r) {
        int oc = wv * 16 + kg * 4 + r;
        t4[r] = (_Float16)gelu_f(acc[r] * (1.0f / 16.0f) + bias[oc]);
    }
    if (MODE == 0) {
        _Float16* dst = outH + (size_t)b * 70 * 72 * 128 +
                        ((size_t)(h + 3) * 72 + (3 + w)) * 128 + wv * 16 + kg * 4;
        *(half4*)dst = t4;
    } else {
        *(half4*)(outH + ((size_t)(b * HWSZ) + p) * 128 + wv * 16 + kg * 4) = t4;
    }
}

// ---------------- KZ: z = gelu(a) * g  (CL f16)
__global__ __launch_bounds__(256) void kz_cl(const _Float16* __restrict__ a5cl,
                                             const _Float16* __restrict__ gcl,
                                             _Float16* __restrict__ zbuf) {
    int idx = blockIdx.x * 256 + threadIdx.x;  // half8 index, 131072 total
    half8 a = ((const half8*)a5cl)[idx];
    half8 g = ((const half8*)gcl)[idx];
    half8 z;
#pragma unroll
    for (int j = 0; j < 8; ++j) z[j] = (_Float16)(gelu_f((float)a[j]) * (float)g[j]);
    ((half8*)zbuf)[idx] = z;
}

// ---------------- K6: out(B,HW,32) = z_cl(B,HW,128) @ w2(128,32) + b2
__global__ __launch_bounds__(256) void k6_cl(const _Float16* __restrict__ zbuf,
                                             const float* __restrict__ w2,
                                             const float* __restrict__ b2,
                                             float* __restrict__ out) {
    int idx = blockIdx.x * 256 + threadIdx.x;  // (b,p,d)
    int d = idx & 31;
    int p = (idx >> 5) & 4095;
    int b = idx >> 17;
    const _Float16* zr = zbuf + ((size_t)(b * HWSZ) + p) * 128;
    float acc = b2[d];
#pragma unroll
    for (int c8 = 0; c8 < 16; ++c8) {
        half8 v = *(const half8*)(zr + c8 * 8);
#pragma unroll
        for (int j = 0; j < 8; ++j) acc = fmaf((float)v[j], w2[(c8 * 8 + j) * 32 + d], acc);
    }
    out[idx] = acc;
}

extern "C" void kernel_launch(void* const* d_in, const int* in_sizes, int n_in,
                              void* d_out, int out_size, void* d_ws, size_t ws_size,
                              hipStream_t stream) {
    const float* x   = (const float*)d_in[0];
    const float* w1  = (const float*)d_in[1];
    const float* b1  = (const float*)d_in[2];
    const float* dww = (const float*)d_in[3];
    const float* dwb = (const float*)d_in[4];
    const float* pww = (const float*)d_in[5];
    const float* pwb = (const float*)d_in[6];
    const float* o3w = (const float*)d_in[7];
    const float* o3b = (const float*)d_in[8];
    const float* d3w = (const float*)d_in[9];
    const float* d3b = (const float*)d_in[10];
    const float* o4w = (const float*)d_in[11];
    const float* o4b = (const float*)d_in[12];
    const float* d4w = (const float*)d_in[13];
    const float* d4b = (const float*)d_in[14];
    const float* o5w = (const float*)d_in[15];
    const float* o5b = (const float*)d_in[16];
    const float* d5w = (const float*)d_in[17];
    const float* d5b = (const float*)d_in[18];
    const float* w2  = (const float*)d_in[19];
    const float* b2  = (const float*)d_in[20];

    float* ws = (float*)d_ws;
    float* offb = ws;                              // 1,048,576 f32
    _Float16* clA  = (_Float16*)(ws + 1048576);    // 1,290,240 f16
    _Float16* clB  = (_Float16*)(ws + 1693696);    // 1,290,240 f16
    _Float16* xicl = (_Float16*)(ws + 2338816);    // 1,048,576 f16
    _Float16* dcl  = (_Float16*)(ws + 2863104);    // 1,048,576 f16
    _Float16* gcl  = (_Float16*)(ws + 3387392);    // 1,048,576 f16
    _Float16* a5cl = (_Float16*)(ws + 3911680);    // 1,048,576 f16
    _Float16* zbuf = (_Float16*)(ws + 4435968);    // 1,048,576 f16
    _Float16* wA3  = (_Float16*)(ws + 4960256);    // 49*128*128 f16
    _Float16* wA4  = (_Float16*)(ws + 5361664);    // 9*32*128
    _Float16* wA5  = (_Float16*)(ws + 5380096);    // 25*64*128
    _Float16* wM3  = (_Float16*)(ws + 5482496);    // 49*128*128
    _Float16* wM4  = (_Float16*)(ws + 5883904);    // 9*128*128
    _Float16* wM5  = (_Float16*)(ws + 5957632);    // 25*128*128
    _Float16* dwt  = (_Float16*)(ws + 6162432);    // 9*128
    _Float16* pwt  = (_Float16*)(ws + 6163008);    // 256*128

    // weight transforms
    dwtk<<<5, 256, 0, stream>>>(dww, dwt);
    pcast<<<128, 256, 0, stream>>>(pww, pwt);
    wtr<<<3136, 256, 0, stream>>>(o3w, wA3, 49, 128, 98, 256.f);
    wtr<<<144,  256, 0, stream>>>(o4w, wA4, 9,  32,  18, 256.f);
    wtr<<<800,  256, 0, stream>>>(o5w, wA5, 25, 64,  50, 256.f);
    wtr<<<3136, 256, 0, stream>>>(d3w, wM3, 49, 128, 128, 16.f);
    wtr<<<576,  256, 0, stream>>>(d4w, wM4, 9,  128, 128, 16.f);
    wtr<<<1600, 256, 0, stream>>>(d5w, wM5, 25, 128, 128, 16.f);
    zcl<<<2520, 256, 0, stream>>>((unsigned int*)clA);
    zcl<<<2520, 256, 0, stream>>>((unsigned int*)clB);

    // front of net
    k1_cl<<<4096, 256, 0, stream>>>(x, w1, b1, xicl);
    k2_cl<<<512, 256, 0, stream>>>(xicl, dwt, dwb, dcl);
    k3G<<<dim3(512, 2), 512, 0, stream>>>(dcl, pwt, pwb, clA, gcl);

    // d3: k=7, pad=3, T=49; off M padded 98->128 (MT=8, NA=2, WPX=32)
    k4Gv3<7, 3, 49, 8, 1, 2, 32><<<256, 512, 0, stream>>>(clA, wA3, o3b, offb, 98);
    k5Gv4<7, 3, 49, 0><<<512, 512, 0, stream>>>(clA, offb, 128, wM3, d3b, clB);

    // d4: k=3, pad=1, T=9; OCp=32 (MT=2, NG=4, NA=1, WPX=64)
    k4Gv3<3, 1, 9, 2, 4, 1, 64><<<128, 512, 0, stream>>>(clB, wA4, o4b, offb, 18);
    k5Gv4<3, 1, 9, 0><<<512, 512, 0, stream>>>(clB, offb, 32, wM4, d4b, clA);

    // d5: k=5, pad=2, T=25; OCp=64 (MT=4, NG=2, NA=1, WPX=32) -> flat CL f16
    k4Gv3<5, 2, 25, 4, 2, 1, 32><<<256, 512, 0, stream>>>(clA, wA5, o5b, offb, 50);
    k5Gv4<5, 2, 25, 2><<<512, 512, 0, stream>>>(clA, offb, 64, wM5, d5b, a5cl);

    // tail
    kz_cl<<<512, 256, 0, stream>>>(a5cl, gcl, zbuf);
    k6_cl<<<1024, 256, 0, stream>>>(zbuf, w2, b2, (float*)d_out);
}

// Round 7
// 299.914 us; speedup vs baseline: 1.1669x; 1.1669x over previous
//
#include <hip/hip_runtime.h>
#include <hip/hip_bf16.h>

// Shapes: B=2, H=W=64, HW=4096, DIM=32, HID=128
#define HWSZ 4096

typedef _Float16 half8 __attribute__((ext_vector_type(8)));
typedef _Float16 half4 __attribute__((ext_vector_type(4)));
typedef float f32x4 __attribute__((ext_vector_type(4)));

__device__ __forceinline__ float gelu_f(float v) {
    return 0.5f * v * (1.0f + erff(v * 0.7071067811865475f));
}

// ---------------- K1: x(B,HW,32) @ w1(32,128) + b1, gelu -> CL f16 (B,HW,128)
__global__ __launch_bounds__(256) void k1_cl(const float* __restrict__ x,
                                             const float* __restrict__ w1,
                                             const float* __restrict__ b1,
                                             _Float16* __restrict__ xicl) {
    int idx = blockIdx.x * 256 + threadIdx.x;  // (b,p,c)
    int c = idx & 127;
    int p = (idx >> 7) & 4095;
    int b = idx >> 19;
    const float* xr = x + (size_t)(b * HWSZ + p) * 32;
    float acc = b1[c];
#pragma unroll
    for (int k = 0; k < 32; ++k) acc = fmaf(xr[k], w1[k * 128 + c], acc);
    xicl[idx] = (_Float16)gelu_f(acc);
}

// ---------------- dwt transform: dww (128,1,3,3) f32 -> (9,128) f16
__global__ __launch_bounds__(256) void dwtk(const float* __restrict__ dww,
                                            _Float16* __restrict__ dwt) {
    int idx = blockIdx.x * 256 + threadIdx.x;
    if (idx >= 9 * 128) return;
    int c = idx & 127, j = idx >> 7;
    dwt[j * 128 + c] = (_Float16)dww[c * 9 + j];
}

// ---------------- pwt cast: pww (256,128) f32 -> f16 same layout
__global__ __launch_bounds__(256) void pcast(const float* __restrict__ pww,
                                             _Float16* __restrict__ pwt) {
    int idx = blockIdx.x * 256 + threadIdx.x;  // 32768
    pwt[idx] = (_Float16)pww[idx];
}

// ---------------- K2: depthwise 3x3 (pad 1) + bias, CL f16 in/out
__global__ __launch_bounds__(256) void k2_cl(const _Float16* __restrict__ xicl,
                                             const _Float16* __restrict__ dwt,
                                             const float* __restrict__ dwb,
                                             _Float16* __restrict__ dcl) {
    int idx = blockIdx.x * 256 + threadIdx.x;  // (b,p,cg)
    int cg = idx & 15;
    int p = (idx >> 4) & 4095;
    int b = idx >> 16;
    int h = p >> 6, w = p & 63;
    const _Float16* base = xicl + (size_t)b * HWSZ * 128;
    float acc[8];
#pragma unroll
    for (int j = 0; j < 8; ++j) acc[j] = 0.f;
#pragma unroll
    for (int i = 0; i < 3; ++i) {
        int y = h + i - 1;
        if ((unsigned)y > 63u) continue;
#pragma unroll
        for (int j2 = 0; j2 < 3; ++j2) {
            int xx = w + j2 - 1;
            if ((unsigned)xx > 63u) continue;
            half8 v = *(const half8*)(base + ((size_t)(y * 64 + xx)) * 128 + cg * 8);
            half8 wv8 = *(const half8*)(dwt + (i * 3 + j2) * 128 + cg * 8);
#pragma unroll
            for (int j = 0; j < 8; ++j) acc[j] = fmaf((float)v[j], (float)wv8[j], acc[j]);
        }
    }
    half8 o;
#pragma unroll
    for (int j = 0; j < 8; ++j) o[j] = (_Float16)(acc[j] + dwb[cg * 8 + j]);
    *(half8*)(dcl + ((size_t)(b * HWSZ) + p) * 128 + cg * 8) = o;
}

// ---------------- K3G: pointwise 128->256 MFMA GEMM + bias + gelu
__global__ __launch_bounds__(512) void k3G(const _Float16* __restrict__ dcl,
                                           const _Float16* __restrict__ pwt,
                                           const float* __restrict__ pwb,
                                           _Float16* __restrict__ clA,
                                           _Float16* __restrict__ gcl) {
    int tid = threadIdx.x;
    int wv = tid >> 6;
    int l = tid & 63;
    int col = l & 15, kg = l >> 4;
    int blk = blockIdx.x;
    int hf = blockIdx.y;  // 0:a 1:g
    int b = blk >> 8;
    int px0 = (blk & 255) << 4;
    int p = px0 + col;
    const _Float16* bp = dcl + ((size_t)(b * HWSZ) + p) * 128 + kg * 8;
    int oc0 = hf * 128 + wv * 16;
    const _Float16* ap = pwt + (size_t)(oc0 + col) * 128 + kg * 8;
    f32x4 acc = (f32x4){0.f, 0.f, 0.f, 0.f};
#pragma unroll
    for (int cc = 0; cc < 4; ++cc) {
        half8 bf = *(const half8*)(bp + cc * 32);
        half8 af = *(const half8*)(ap + cc * 32);
        acc = __builtin_amdgcn_mfma_f32_16x16x32_f16(af, bf, acc, 0, 0, 0);
    }
    int h = p >> 6, w = p & 63;
    half4 t4;
#pragma unroll
    for (int r = 0; r < 4; ++r) {
        int oc = oc0 + kg * 4 + r;
        t4[r] = (_Float16)gelu_f(acc[r] + pwb[oc]);
    }
    if (hf == 0) {
        _Float16* dst = clA + (size_t)b * 70 * 72 * 128 +
                        ((size_t)(h + 3) * 72 + (w + 3)) * 128 + wv * 16 + kg * 4;
        *(half4*)dst = t4;
    } else {
        *(half4*)(gcl + ((size_t)(b * HWSZ) + p) * 128 + wv * 16 + kg * 4) = t4;
    }
}

// ---------------- zero a channels-last padded buffer (as uints)
__global__ __launch_bounds__(256) void zcl(unsigned int* __restrict__ p) {
    p[blockIdx.x * 256 + threadIdx.x] = 0u;
}

// ---------------- weight transform: (O,128,T) f32 -> (T,Op,128) f16, scaled, zero-pad rows
__global__ __launch_bounds__(256) void wtr(const float* __restrict__ w,
                                           _Float16* __restrict__ o,
                                           int T, int Op, int O, float scale) {
    int idx = blockIdx.x * 256 + threadIdx.x;  // (t, op, c)
    int c = idx & 127;
    int op = (idx >> 7) % Op;
    int t = idx / (128 * Op);
    float v = (op < O) ? w[((size_t)(op * 128 + c)) * T + t] * scale : 0.f;
    o[idx] = (_Float16)v;
}

// ---------------- K4Gv3: offset conv = implicit-im2col MFMA GEMM with LDS-staged B
template <int KK, int PAD, int T, int MT, int NG, int NA, int WPX>
__global__ __launch_bounds__(512) void k4Gv3(const _Float16* __restrict__ cl,
                                             const _Float16* __restrict__ wA,
                                             const float* __restrict__ obias,
                                             float* __restrict__ offb, int OC) {
    constexpr int OCp = MT * 16;
    constexpr int COLS = WPX + KK - 1;
    constexpr int NB = 64 / WPX;  // w0 positions per row
    __shared__ _Float16 bS[KK * COLS * 128];

    int tid = threadIdx.x;
    int blk = blockIdx.x;
    int w0 = (blk % NB) * WPX;
    int h = (blk / NB) & 63;
    int b = blk / (NB * 64);
    const _Float16* clb = cl + (size_t)b * 70 * 72 * 128;

    int hh0 = h + (3 - PAD);
    int ww0 = w0 + (3 - PAD);
    for (int g = tid; g < KK * COLS * 16; g += 512) {
        int r = g / (COLS * 16);
        int rest = g - r * (COLS * 16);
        int c = rest >> 4;
        int s = rest & 15;
        half8 v = *(const half8*)(clb + ((size_t)(hh0 + r) * 72 + (ww0 + c)) * 128 + s * 8);
        *(half8*)&bS[((r * COLS + c) * 16 + (s ^ (c & 7))) * 8] = v;
    }

    int wv = tid >> 6;
    int l = tid & 63;
    int col = l & 15, kg = l >> 4;
    int m = wv % MT;
    int ng = wv / MT;

    const _Float16* apbase = wA + ((size_t)(m * 16 + col)) * 128 + kg * 8;
    half8 afv[4];
#pragma unroll
    for (int cc = 0; cc < 4; ++cc) afv[cc] = *(const half8*)(apbase + cc * 32);

    f32x4 acc[NA];
#pragma unroll
    for (int a = 0; a < NA; ++a) acc[a] = (f32x4){0.f, 0.f, 0.f, 0.f};

    __syncthreads();

    for (int t = 0; t < T; ++t) {
        int ky = t / KK, kx = t - ky * KK;
        half8 afn[4];
        if (t + 1 < T) {
            const _Float16* apn = apbase + (size_t)(t + 1) * OCp * 128;
#pragma unroll
            for (int cc = 0; cc < 4; ++cc) afn[cc] = *(const half8*)(apn + cc * 32);
        }
#pragma unroll
        for (int a = 0; a < NA; ++a) {
            int cw = ng * NA * 16 + a * 16 + col + kx;
#pragma unroll
            for (int cc = 0; cc < 4; ++cc) {
                half8 bf = *(const half8*)&bS[((ky * COLS + cw) * 16 + ((cc * 4 + kg) ^ (cw & 7))) * 8];
                acc[a] = __builtin_amdgcn_mfma_f32_16x16x32_f16(afv[cc], bf, acc[a], 0, 0, 0);
            }
        }
#pragma unroll
        for (int cc = 0; cc < 4; ++cc) afv[cc] = afn[cc];
    }

#pragma unroll
    for (int a = 0; a < NA; ++a) {
        int px = h * 64 + w0 + ng * NA * 16 + a * 16 + col;
#pragma unroll
        for (int r = 0; r < 4; ++r) {
            int oc = m * 16 + kg * 4 + r;
            float v = acc[a][r] * (1.0f / 256.0f) + (oc < OC ? obias[oc] : 0.f);
            offb[((size_t)(b * OCp + oc)) * HWSZ + px] = v;
        }
    }
}

// ---------------- K5Gv5: deformable conv, 32px/block, 2-phase-deep counted-vmcnt pipeline
// MODE 0: write CL f16 padded interior. MODE 2: write CL f16 flat (B,HW,128).
template <int KK, int PAD, int T, int MODE>
__global__ __launch_bounds__(512, 2) void k5Gv5(const _Float16* __restrict__ cl,
                                                const float* __restrict__ offb, int OFFP,
                                                const _Float16* __restrict__ wM,
                                                const float* __restrict__ bias,
                                                _Float16* __restrict__ outH) {
    __shared__ _Float16 panel[2][32][128];  // double-buffered sampled B panel (16 KB)

    int tid = threadIdx.x;
    int blk = blockIdx.x;  // 256 blocks: b = blk>>7, px0 = (blk&127)*32
    int b = blk >> 7;
    int px0 = (blk & 127) << 5;
    const _Float16* clb = cl + (size_t)b * 70 * 72 * 128;
    const float* ob = offb + (size_t)b * OFFP * HWSZ;

    // sampling roles: thread = (pixel, 8-channel slice)
    int px_s = tid >> 4;   // 0..31
    int slice = tid & 15;  // 8 channels
    int p_s = px0 + px_s;
    int h_s = p_s >> 6, w_s = p_s & 63;
    // MFMA roles
    int wv = tid >> 6;
    int l = tid & 63;
    int col = l & 15, kg = l >> 4;

    f32x4 acc0 = (f32x4){0.f, 0.f, 0.f, 0.f};
    f32x4 acc1 = (f32x4){0.f, 0.f, 0.f, 0.f};

    float pwA[4], pwB[4];
    int poA[4], poB[4];  // r0,r1 (row*72*128), c0,c1 (col*128)
    half8 cA[4], cB[4], wA8[4], wB8[4];

    auto PARAMS = [&](int t, float* pw, int* po) {
        int ky = t / KK, kx = t - ky * KK;
        float dy = ob[(size_t)(2 * t) * HWSZ + p_s];
        float dx = ob[(size_t)(2 * t + 1) * HWSZ + p_s];
        float py = (float)(h_s + ky - PAD) + dy;
        float pxs = (float)(w_s + kx - PAD) + dx;
        float y0f = floorf(py), x0f = floorf(pxs);
        float wy = py - y0f, wx = pxs - x0f;
        int y0 = (int)y0f, x0 = (int)x0f;
        int y1 = y0 + 1, x1 = x0 + 1;
        bool vy0 = (y0 >= 0) && (y0 < 64), vy1 = (y1 >= 0) && (y1 < 64);
        bool vx0 = (x0 >= 0) && (x0 < 64), vx1 = (x1 >= 0) && (x1 < 64);
        int cy0 = min(max(y0, 0), 63) + 3, cy1 = min(max(y1, 0), 63) + 3;
        int cx0 = min(max(x0, 0), 63) + 3, cx1 = min(max(x1, 0), 63) + 3;
        pw[0] = (vy0 && vx0) ? (1.f - wy) * (1.f - wx) : 0.f;
        pw[1] = (vy0 && vx1) ? (1.f - wy) * wx : 0.f;
        pw[2] = (vy1 && vx0) ? wy * (1.f - wx) : 0.f;
        pw[3] = (vy1 && vx1) ? wy * wx : 0.f;
        po[0] = cy0 * 72 * 128; po[1] = cy1 * 72 * 128;
        po[2] = cx0 * 128;      po[3] = cx1 * 128;
    };
    auto LOADC = [&](half8* c, const int* po) {
        const _Float16* s = clb + slice * 8;
        c[0] = *(const half8*)(s + po[0] + po[2]);
        c[1] = *(const half8*)(s + po[0] + po[3]);
        c[2] = *(const half8*)(s + po[1] + po[2]);
        c[3] = *(const half8*)(s + po[1] + po[3]);
    };
    auto BLEND = [&](const half8* c, const float* pw, int buf) {
        half8 r;
#pragma unroll
        for (int j = 0; j < 8; ++j) {
            float v = pw[0] * (float)c[0][j] + pw[1] * (float)c[1][j] +
                      pw[2] * (float)c[2][j] + pw[3] * (float)c[3][j];
            r[j] = (_Float16)v;
        }
        *(half8*)&panel[buf][px_s][(slice ^ (px_s & 7)) * 8] = r;
    };
    auto LOADW = [&](half8* w8, int t) {
        const _Float16* ap = wM + ((size_t)t * 128 + wv * 16 + col) * 128 + kg * 8;
#pragma unroll
        for (int cc = 0; cc < 4; ++cc) w8[cc] = *(const half8*)(ap + cc * 32);
    };
    auto MM = [&](const half8* w8, int buf) {
#pragma unroll
        for (int cc = 0; cc < 4; ++cc) {
            half8 bf0 = *(const half8*)&panel[buf][col][((cc * 4 + kg) ^ (col & 7)) * 8];
            acc0 = __builtin_amdgcn_mfma_f32_16x16x32_f16(w8[cc], bf0, acc0, 0, 0, 0);
            half8 bf1 = *(const half8*)&panel[buf][16 + col][((cc * 4 + kg) ^ (col & 7)) * 8];
            acc1 = __builtin_amdgcn_mfma_f32_16x16x32_f16(w8[cc], bf1, acc1, 0, 0, 0);
        }
    };
    auto BAR = [&]() {
        asm volatile("s_waitcnt lgkmcnt(0)" ::: "memory");
        __builtin_amdgcn_s_barrier();
        __builtin_amdgcn_sched_barrier(0);
    };

    // ---- prologue: tap0 blended now; cA re-armed with tap2; cB holds tap1; W0/W1 in regs
    PARAMS(0, pwA, poA);
    LOADC(cA, poA);
    PARAMS(1, pwB, poB);
    LOADC(cB, poB);
    LOADW(wA8, 0);
    LOADW(wB8, 1 < T ? 1 : 0);
    BLEND(cA, pwA, 0);
    if (2 < T) { PARAMS(2, pwA, poA); LOADC(cA, poA); }
    BAR();

    for (int t = 0; t < T; t += 2) {
        // even phase: compute tap t
        MM(wA8, t & 1);
        if (t + 2 < T) LOADW(wA8, t + 2);
        if (t + 1 < T) BLEND(cB, pwB, (t + 1) & 1);
        if (t + 3 < T) { PARAMS(t + 3, pwB, poB); LOADC(cB, poB); }
        BAR();
        if (t + 1 < T) {
            // odd phase: compute tap t+1
            MM(wB8, (t + 1) & 1);
            if (t + 3 < T) LOADW(wB8, t + 3);
            if (t + 2 < T) BLEND(cA, pwA, (t + 2) & 1);
            if (t + 4 < T) { PARAMS(t + 4, pwA, poA); LOADC(cA, poA); }
            BAR();
        }
    }

    // ---- epilogue
#pragma unroll
    for (int n = 0; n < 2; ++n) {
        f32x4 acc = n ? acc1 : acc0;
        int p = px0 + n * 16 + col;
        int h = p >> 6, w = p & 63;
        half4 t4;
#pragma unroll
        for (int r = 0; r < 4; ++r) {
            int oc = wv * 16 + kg * 4 + r;
            t4[r] = (_Float16)gelu_f(acc[r] * (1.0f / 16.0f) + bias[oc]);
        }
        if (MODE == 0) {
            _Float16* dst = outH + (size_t)b * 70 * 72 * 128 +
                            ((size_t)(h + 3) * 72 + (3 + w)) * 128 + wv * 16 + kg * 4;
            *(half4*)dst = t4;
        } else {
            *(half4*)(outH + ((size_t)(b * HWSZ) + p) * 128 + wv * 16 + kg * 4) = t4;
        }
    }
}

// ---------------- KZ: z = gelu(a) * g  (CL f16)
__global__ __launch_bounds__(256) void kz_cl(const _Float16* __restrict__ a5cl,
                                             const _Float16* __restrict__ gcl,
                                             _Float16* __restrict__ zbuf) {
    int idx = blockIdx.x * 256 + threadIdx.x;  // half8 index, 131072 total
    half8 a = ((const half8*)a5cl)[idx];
    half8 g = ((const half8*)gcl)[idx];
    half8 z;
#pragma unroll
    for (int j = 0; j < 8; ++j) z[j] = (_Float16)(gelu_f((float)a[j]) * (float)g[j]);
    ((half8*)zbuf)[idx] = z;
}

// ---------------- K6: out(B,HW,32) = z_cl(B,HW,128) @ w2(128,32) + b2
__global__ __launch_bounds__(256) void k6_cl(const _Float16* __restrict__ zbuf,
                                             const float* __restrict__ w2,
                                             const float* __restrict__ b2,
                                             float* __restrict__ out) {
    int idx = blockIdx.x * 256 + threadIdx.x;  // (b,p,d)
    int d = idx & 31;
    int p = (idx >> 5) & 4095;
    int b = idx >> 17;
    const _Float16* zr = zbuf + ((size_t)(b * HWSZ) + p) * 128;
    float acc = b2[d];
#pragma unroll
    for (int c8 = 0; c8 < 16; ++c8) {
        half8 v = *(const half8*)(zr + c8 * 8);
#pragma unroll
        for (int j = 0; j < 8; ++j) acc = fmaf((float)v[j], w2[(c8 * 8 + j) * 32 + d], acc);
    }
    out[idx] = acc;
}

extern "C" void kernel_launch(void* const* d_in, const int* in_sizes, int n_in,
                              void* d_out, int out_size, void* d_ws, size_t ws_size,
                              hipStream_t stream) {
    const float* x   = (const float*)d_in[0];
    const float* w1  = (const float*)d_in[1];
    const float* b1  = (const float*)d_in[2];
    const float* dww = (const float*)d_in[3];
    const float* dwb = (const float*)d_in[4];
    const float* pww = (const float*)d_in[5];
    const float* pwb = (const float*)d_in[6];
    const float* o3w = (const float*)d_in[7];
    const float* o3b = (const float*)d_in[8];
    const float* d3w = (const float*)d_in[9];
    const float* d3b = (const float*)d_in[10];
    const float* o4w = (const float*)d_in[11];
    const float* o4b = (const float*)d_in[12];
    const float* d4w = (const float*)d_in[13];
    const float* d4b = (const float*)d_in[14];
    const float* o5w = (const float*)d_in[15];
    const float* o5b = (const float*)d_in[16];
    const float* d5w = (const float*)d_in[17];
    const float* d5b = (const float*)d_in[18];
    const float* w2  = (const float*)d_in[19];
    const float* b2  = (const float*)d_in[20];

    float* ws = (float*)d_ws;
    float* offb = ws;                              // 1,048,576 f32
    _Float16* clA  = (_Float16*)(ws + 1048576);    // 1,290,240 f16
    _Float16* clB  = (_Float16*)(ws + 1693696);    // 1,290,240 f16
    _Float16* xicl = (_Float16*)(ws + 2338816);    // 1,048,576 f16
    _Float16* dcl  = (_Float16*)(ws + 2863104);    // 1,048,576 f16
    _Float16* gcl  = (_Float16*)(ws + 3387392);    // 1,048,576 f16
    _Float16* a5cl = (_Float16*)(ws + 3911680);    // 1,048,576 f16
    _Float16* zbuf = (_Float16*)(ws + 4435968);    // 1,048,576 f16
    _Float16* wA3  = (_Float16*)(ws + 4960256);    // 49*128*128 f16
    _Float16* wA4  = (_Float16*)(ws + 5361664);    // 9*32*128
    _Float16* wA5  = (_Float16*)(ws + 5380096);    // 25*64*128
    _Float16* wM3  = (_Float16*)(ws + 5482496);    // 49*128*128
    _Float16* wM4  = (_Float16*)(ws + 5883904);    // 9*128*128
    _Float16* wM5  = (_Float16*)(ws + 5957632);    // 25*128*128
    _Float16* dwt  = (_Float16*)(ws + 6162432);    // 9*128
    _Float16* pwt  = (_Float16*)(ws + 6163008);    // 256*128

    // weight transforms
    dwtk<<<5, 256, 0, stream>>>(dww, dwt);
    pcast<<<128, 256, 0, stream>>>(pww, pwt);
    wtr<<<3136, 256, 0, stream>>>(o3w, wA3, 49, 128, 98, 256.f);
    wtr<<<144,  256, 0, stream>>>(o4w, wA4, 9,  32,  18, 256.f);
    wtr<<<800,  256, 0, stream>>>(o5w, wA5, 25, 64,  50, 256.f);
    wtr<<<3136, 256, 0, stream>>>(d3w, wM3, 49, 128, 128, 16.f);
    wtr<<<576,  256, 0, stream>>>(d4w, wM4, 9,  128, 128, 16.f);
    wtr<<<1600, 256, 0, stream>>>(d5w, wM5, 25, 128, 128, 16.f);
    zcl<<<2520, 256, 0, stream>>>((unsigned int*)clA);
    zcl<<<2520, 256, 0, stream>>>((unsigned int*)clB);

    // front of net
    k1_cl<<<4096, 256, 0, stream>>>(x, w1, b1, xicl);
    k2_cl<<<512, 256, 0, stream>>>(xicl, dwt, dwb, dcl);
    k3G<<<dim3(512, 2), 512, 0, stream>>>(dcl, pwt, pwb, clA, gcl);

    // d3: k=7, pad=3, T=49; off M padded 98->128 (MT=8, NA=2, WPX=32)
    k4Gv3<7, 3, 49, 8, 1, 2, 32><<<256, 512, 0, stream>>>(clA, wA3, o3b, offb, 98);
    k5Gv5<7, 3, 49, 0><<<256, 512, 0, stream>>>(clA, offb, 128, wM3, d3b, clB);

    // d4: k=3, pad=1, T=9; OCp=32 (MT=2, NG=4, NA=1, WPX=64)
    k4Gv3<3, 1, 9, 2, 4, 1, 64><<<128, 512, 0, stream>>>(clB, wA4, o4b, offb, 18);
    k5Gv5<3, 1, 9, 0><<<256, 512, 0, stream>>>(clB, offb, 32, wM4, d4b, clA);

    // d5: k=5, pad=2, T=25; OCp=64 (MT=4, NG=2, NA=1, WPX=32) -> flat CL f16
    k4Gv3<5, 2, 25, 4, 2, 1, 32><<<256, 512, 0, stream>>>(clA, wA5, o5b, offb, 50);
    k5Gv5<5, 2, 25, 2><<<256, 512, 0, stream>>>(clA, offb, 64, wM5, d5b, a5cl);

    // tail
    kz_cl<<<512, 256, 0, stream>>>(a5cl, gcl, zbuf);
    k6_cl<<<1024, 256, 0, stream>>>(zbuf, w2, b2, (float*)d_out);
}

// Round 8
// 283.587 us; speedup vs baseline: 1.2341x; 1.0576x over previous
//
#include <hip/hip_runtime.h>
#include <hip/hip_bf16.h>

// Shapes: B=2, H=W=64, HW=4096, DIM=32, HID=128
#define HWSZ 4096

typedef _Float16 half8 __attribute__((ext_vector_type(8)));
typedef _Float16 half4 __attribute__((ext_vector_type(4)));
typedef float f32x4 __attribute__((ext_vector_type(4)));

__device__ __forceinline__ float gelu_f(float v) {
    return 0.5f * v * (1.0f + erff(v * 0.7071067811865475f));
}

// ---------------- K1: x(B,HW,32) @ w1(32,128) + b1, gelu -> CL f16 (B,HW,128)
__global__ __launch_bounds__(256) void k1_cl(const float* __restrict__ x,
                                             const float* __restrict__ w1,
                                             const float* __restrict__ b1,
                                             _Float16* __restrict__ xicl) {
    int idx = blockIdx.x * 256 + threadIdx.x;  // (b,p,c)
    int c = idx & 127;
    int p = (idx >> 7) & 4095;
    int b = idx >> 19;
    const float* xr = x + (size_t)(b * HWSZ + p) * 32;
    float acc = b1[c];
#pragma unroll
    for (int k = 0; k < 32; ++k) acc = fmaf(xr[k], w1[k * 128 + c], acc);
    xicl[idx] = (_Float16)gelu_f(acc);
}

// ---------------- dwt transform: dww (128,1,3,3) f32 -> (9,128) f16
__global__ __launch_bounds__(256) void dwtk(const float* __restrict__ dww,
                                            _Float16* __restrict__ dwt) {
    int idx = blockIdx.x * 256 + threadIdx.x;
    if (idx >= 9 * 128) return;
    int c = idx & 127, j = idx >> 7;
    dwt[j * 128 + c] = (_Float16)dww[c * 9 + j];
}

// ---------------- pwt cast: pww (256,128) f32 -> f16 same layout
__global__ __launch_bounds__(256) void pcast(const float* __restrict__ pww,
                                             _Float16* __restrict__ pwt) {
    int idx = blockIdx.x * 256 + threadIdx.x;  // 32768
    pwt[idx] = (_Float16)pww[idx];
}

// ---------------- K2: depthwise 3x3 (pad 1) + bias, CL f16 in/out
__global__ __launch_bounds__(256) void k2_cl(const _Float16* __restrict__ xicl,
                                             const _Float16* __restrict__ dwt,
                                             const float* __restrict__ dwb,
                                             _Float16* __restrict__ dcl) {
    int idx = blockIdx.x * 256 + threadIdx.x;  // (b,p,cg)
    int cg = idx & 15;
    int p = (idx >> 4) & 4095;
    int b = idx >> 16;
    int h = p >> 6, w = p & 63;
    const _Float16* base = xicl + (size_t)b * HWSZ * 128;
    float acc[8];
#pragma unroll
    for (int j = 0; j < 8; ++j) acc[j] = 0.f;
#pragma unroll
    for (int i = 0; i < 3; ++i) {
        int y = h + i - 1;
        if ((unsigned)y > 63u) continue;
#pragma unroll
        for (int j2 = 0; j2 < 3; ++j2) {
            int xx = w + j2 - 1;
            if ((unsigned)xx > 63u) continue;
            half8 v = *(const half8*)(base + ((size_t)(y * 64 + xx)) * 128 + cg * 8);
            half8 wv8 = *(const half8*)(dwt + (i * 3 + j2) * 128 + cg * 8);
#pragma unroll
            for (int j = 0; j < 8; ++j) acc[j] = fmaf((float)v[j], (float)wv8[j], acc[j]);
        }
    }
    half8 o;
#pragma unroll
    for (int j = 0; j < 8; ++j) o[j] = (_Float16)(acc[j] + dwb[cg * 8 + j]);
    *(half8*)(dcl + ((size_t)(b * HWSZ) + p) * 128 + cg * 8) = o;
}

// ---------------- K3G: pointwise 128->256 MFMA GEMM + bias + gelu
__global__ __launch_bounds__(512) void k3G(const _Float16* __restrict__ dcl,
                                           const _Float16* __restrict__ pwt,
                                           const float* __restrict__ pwb,
                                           _Float16* __restrict__ clA,
                                           _Float16* __restrict__ gcl) {
    int tid = threadIdx.x;
    int wv = tid >> 6;
    int l = tid & 63;
    int col = l & 15, kg = l >> 4;
    int blk = blockIdx.x;
    int hf = blockIdx.y;  // 0:a 1:g
    int b = blk >> 8;
    int px0 = (blk & 255) << 4;
    int p = px0 + col;
    const _Float16* bp = dcl + ((size_t)(b * HWSZ) + p) * 128 + kg * 8;
    int oc0 = hf * 128 + wv * 16;
    const _Float16* ap = pwt + (size_t)(oc0 + col) * 128 + kg * 8;
    f32x4 acc = (f32x4){0.f, 0.f, 0.f, 0.f};
#pragma unroll
    for (int cc = 0; cc < 4; ++cc) {
        half8 bf = *(const half8*)(bp + cc * 32);
        half8 af = *(const half8*)(ap + cc * 32);
        acc = __builtin_amdgcn_mfma_f32_16x16x32_f16(af, bf, acc, 0, 0, 0);
    }
    int h = p >> 6, w = p & 63;
    half4 t4;
#pragma unroll
    for (int r = 0; r < 4; ++r) {
        int oc = oc0 + kg * 4 + r;
        t4[r] = (_Float16)gelu_f(acc[r] + pwb[oc]);
    }
    if (hf == 0) {
        _Float16* dst = clA + (size_t)b * 70 * 72 * 128 +
                        ((size_t)(h + 3) * 72 + (w + 3)) * 128 + wv * 16 + kg * 4;
        *(half4*)dst = t4;
    } else {
        *(half4*)(gcl + ((size_t)(b * HWSZ) + p) * 128 + wv * 16 + kg * 4) = t4;
    }
}

// ---------------- zero a channels-last padded buffer (as uints)
__global__ __launch_bounds__(256) void zcl(unsigned int* __restrict__ p) {
    p[blockIdx.x * 256 + threadIdx.x] = 0u;
}

// ---------------- weight transform: (O,128,T) f32 -> (T,Op,128) f16, scaled, zero-pad rows
__global__ __launch_bounds__(256) void wtr(const float* __restrict__ w,
                                           _Float16* __restrict__ o,
                                           int T, int Op, int O, float scale) {
    int idx = blockIdx.x * 256 + threadIdx.x;  // (t, op, c)
    int c = idx & 127;
    int op = (idx >> 7) % Op;
    int t = idx / (128 * Op);
    float v = (op < O) ? w[((size_t)(op * 128 + c)) * T + t] * scale : 0.f;
    o[idx] = (_Float16)v;
}

// ---------------- K4Gv3: offset conv = implicit-im2col MFMA GEMM with LDS-staged B
template <int KK, int PAD, int T, int MT, int NG, int NA, int WPX>
__global__ __launch_bounds__(512) void k4Gv3(const _Float16* __restrict__ cl,
                                             const _Float16* __restrict__ wA,
                                             const float* __restrict__ obias,
                                             float* __restrict__ offb, int OC) {
    constexpr int OCp = MT * 16;
    constexpr int COLS = WPX + KK - 1;
    constexpr int NB = 64 / WPX;  // w0 positions per row
    __shared__ _Float16 bS[KK * COLS * 128];

    int tid = threadIdx.x;
    int blk = blockIdx.x;
    int w0 = (blk % NB) * WPX;
    int h = (blk / NB) & 63;
    int b = blk / (NB * 64);
    const _Float16* clb = cl + (size_t)b * 70 * 72 * 128;

    int hh0 = h + (3 - PAD);
    int ww0 = w0 + (3 - PAD);
    for (int g = tid; g < KK * COLS * 16; g += 512) {
        int r = g / (COLS * 16);
        int rest = g - r * (COLS * 16);
        int c = rest >> 4;
        int s = rest & 15;
        half8 v = *(const half8*)(clb + ((size_t)(hh0 + r) * 72 + (ww0 + c)) * 128 + s * 8);
        *(half8*)&bS[((r * COLS + c) * 16 + (s ^ (c & 7))) * 8] = v;
    }

    int wv = tid >> 6;
    int l = tid & 63;
    int col = l & 15, kg = l >> 4;
    int m = wv % MT;
    int ng = wv / MT;

    const _Float16* apbase = wA + ((size_t)(m * 16 + col)) * 128 + kg * 8;
    half8 afv[4];
#pragma unroll
    for (int cc = 0; cc < 4; ++cc) afv[cc] = *(const half8*)(apbase + cc * 32);

    f32x4 acc[NA];
#pragma unroll
    for (int a = 0; a < NA; ++a) acc[a] = (f32x4){0.f, 0.f, 0.f, 0.f};

    __syncthreads();

    for (int t = 0; t < T; ++t) {
        int ky = t / KK, kx = t - ky * KK;
        half8 afn[4];
        if (t + 1 < T) {
            const _Float16* apn = apbase + (size_t)(t + 1) * OCp * 128;
#pragma unroll
            for (int cc = 0; cc < 4; ++cc) afn[cc] = *(const half8*)(apn + cc * 32);
        }
#pragma unroll
        for (int a = 0; a < NA; ++a) {
            int cw = ng * NA * 16 + a * 16 + col + kx;
#pragma unroll
            for (int cc = 0; cc < 4; ++cc) {
                half8 bf = *(const half8*)&bS[((ky * COLS + cw) * 16 + ((cc * 4 + kg) ^ (cw & 7))) * 8];
                acc[a] = __builtin_amdgcn_mfma_f32_16x16x32_f16(afv[cc], bf, acc[a], 0, 0, 0);
            }
        }
#pragma unroll
        for (int cc = 0; cc < 4; ++cc) afv[cc] = afn[cc];
    }

#pragma unroll
    for (int a = 0; a < NA; ++a) {
        int px = h * 64 + w0 + ng * NA * 16 + a * 16 + col;
#pragma unroll
        for (int r = 0; r < 4; ++r) {
            int oc = m * 16 + kg * 4 + r;
            float v = acc[a][r] * (1.0f / 256.0f) + (oc < OC ? obias[oc] : 0.f);
            offb[((size_t)(b * OCp + oc)) * HWSZ + px] = v;
        }
    }
}

// ---------------- K5Gv6: deformable conv, split-T (2 co-resident chunks), f32 partials
// grid (256, 2): y = tap chunk. Writes raw f32 partials to pbuf[chunk].
template <int KK, int PAD, int TMID, int T>
__global__ __launch_bounds__(512, 4) void k5Gv6(const _Float16* __restrict__ cl,
                                                const float* __restrict__ offb, int OFFP,
                                                const _Float16* __restrict__ wM,
                                                float* __restrict__ pbuf) {
    __shared__ _Float16 panel[2][32][128];  // double-buffered sampled B panel (16 KB)

    int tid = threadIdx.x;
    int blk = blockIdx.x;
    int chunk = blockIdx.y;
    int TS = chunk ? TMID : 0;
    int TE = chunk ? T : TMID;
    int b = blk >> 7;
    int px0 = (blk & 127) << 5;
    const _Float16* clb = cl + (size_t)b * 70 * 72 * 128;
    const float* ob = offb + (size_t)b * OFFP * HWSZ;

    // sampling roles: thread = (pixel, 8-channel slice)
    int px_s = tid >> 4;   // 0..31
    int slice = tid & 15;  // 8 channels
    int p_s = px0 + px_s;
    int h_s = p_s >> 6, w_s = p_s & 63;
    // MFMA roles
    int wv = tid >> 6;
    int l = tid & 63;
    int col = l & 15, kg = l >> 4;

    f32x4 acc0 = (f32x4){0.f, 0.f, 0.f, 0.f};
    f32x4 acc1 = (f32x4){0.f, 0.f, 0.f, 0.f};

    float pwA[4], pwB[4];
    int poA[4], poB[4];
    half8 cA[4], cB[4], wA8[4], wB8[4];

    auto PARAMS = [&](int t, float* pw, int* po) {
        int ky = t / KK, kx = t - ky * KK;
        float dy = ob[(size_t)(2 * t) * HWSZ + p_s];
        float dx = ob[(size_t)(2 * t + 1) * HWSZ + p_s];
        float py = (float)(h_s + ky - PAD) + dy;
        float pxs = (float)(w_s + kx - PAD) + dx;
        float y0f = floorf(py), x0f = floorf(pxs);
        float wy = py - y0f, wx = pxs - x0f;
        int y0 = (int)y0f, x0 = (int)x0f;
        int y1 = y0 + 1, x1 = x0 + 1;
        bool vy0 = (y0 >= 0) && (y0 < 64), vy1 = (y1 >= 0) && (y1 < 64);
        bool vx0 = (x0 >= 0) && (x0 < 64), vx1 = (x1 >= 0) && (x1 < 64);
        int cy0 = min(max(y0, 0), 63) + 3, cy1 = min(max(y1, 0), 63) + 3;
        int cx0 = min(max(x0, 0), 63) + 3, cx1 = min(max(x1, 0), 63) + 3;
        pw[0] = (vy0 && vx0) ? (1.f - wy) * (1.f - wx) : 0.f;
        pw[1] = (vy0 && vx1) ? (1.f - wy) * wx : 0.f;
        pw[2] = (vy1 && vx0) ? wy * (1.f - wx) : 0.f;
        pw[3] = (vy1 && vx1) ? wy * wx : 0.f;
        po[0] = cy0 * 72 * 128; po[1] = cy1 * 72 * 128;
        po[2] = cx0 * 128;      po[3] = cx1 * 128;
    };
    auto LOADC = [&](half8* c, const int* po) {
        const _Float16* s = clb + slice * 8;
        c[0] = *(const half8*)(s + po[0] + po[2]);
        c[1] = *(const half8*)(s + po[0] + po[3]);
        c[2] = *(const half8*)(s + po[1] + po[2]);
        c[3] = *(const half8*)(s + po[1] + po[3]);
    };
    auto BLEND = [&](const half8* c, const float* pw, int buf) {
        half8 r;
#pragma unroll
        for (int j = 0; j < 8; ++j) {
            float v = pw[0] * (float)c[0][j] + pw[1] * (float)c[1][j] +
                      pw[2] * (float)c[2][j] + pw[3] * (float)c[3][j];
            r[j] = (_Float16)v;
        }
        *(half8*)&panel[buf][px_s][(slice ^ (px_s & 7)) * 8] = r;
    };
    auto LOADW = [&](half8* w8, int t) {
        const _Float16* ap = wM + ((size_t)t * 128 + wv * 16 + col) * 128 + kg * 8;
#pragma unroll
        for (int cc = 0; cc < 4; ++cc) w8[cc] = *(const half8*)(ap + cc * 32);
    };
    auto MM = [&](const half8* w8, int buf) {
#pragma unroll
        for (int cc = 0; cc < 4; ++cc) {
            half8 bf0 = *(const half8*)&panel[buf][col][((cc * 4 + kg) ^ (col & 7)) * 8];
            acc0 = __builtin_amdgcn_mfma_f32_16x16x32_f16(w8[cc], bf0, acc0, 0, 0, 0);
            half8 bf1 = *(const half8*)&panel[buf][16 + col][((cc * 4 + kg) ^ (col & 7)) * 8];
            acc1 = __builtin_amdgcn_mfma_f32_16x16x32_f16(w8[cc], bf1, acc1, 0, 0, 0);
        }
    };
    auto BAR = [&]() {
        asm volatile("s_waitcnt lgkmcnt(0)" ::: "memory");
        __builtin_amdgcn_s_barrier();
        __builtin_amdgcn_sched_barrier(0);
    };

    // ---- prologue
    PARAMS(TS, pwA, poA);
    LOADC(cA, poA);
    if (TS + 1 < TE) { PARAMS(TS + 1, pwB, poB); LOADC(cB, poB); }
    LOADW(wA8, TS);
    if (TS + 1 < TE) LOADW(wB8, TS + 1);
    BLEND(cA, pwA, TS & 1);
    if (TS + 2 < TE) { PARAMS(TS + 2, pwA, poA); LOADC(cA, poA); }
    BAR();

    for (int t = TS; t < TE; t += 2) {
        MM(wA8, t & 1);
        if (t + 2 < TE) LOADW(wA8, t + 2);
        if (t + 1 < TE) BLEND(cB, pwB, (t + 1) & 1);
        if (t + 3 < TE) { PARAMS(t + 3, pwB, poB); LOADC(cB, poB); }
        BAR();
        if (t + 1 < TE) {
            MM(wB8, (t + 1) & 1);
            if (t + 3 < TE) LOADW(wB8, t + 3);
            if (t + 2 < TE) BLEND(cA, pwA, (t + 2) & 1);
            if (t + 4 < TE) { PARAMS(t + 4, pwA, poA); LOADC(cA, poA); }
            BAR();
        }
    }

    // ---- epilogue: raw f32 partials
    float* pb = pbuf + (size_t)chunk * (2 * HWSZ * 128);
#pragma unroll
    for (int n = 0; n < 2; ++n) {
        f32x4 acc = n ? acc1 : acc0;
        int p = px0 + n * 16 + col;
        *(f32x4*)&pb[((size_t)(b * HWSZ) + p) * 128 + wv * 16 + kg * 4] = acc;
    }
}

// ---------------- KRD: reduce partials + bias + gelu -> f16 CL (padded or flat)
template <int OUTMODE>
__global__ __launch_bounds__(256) void krd(const float* __restrict__ pbuf,
                                           const float* __restrict__ bias,
                                           _Float16* __restrict__ outH) {
    int idx = blockIdx.x * 256 + threadIdx.x;  // 262144: (b,p,oc4)
    int oc4 = idx & 31;
    int p = (idx >> 5) & 4095;
    int b = idx >> 17;
    size_t base = ((size_t)(b * HWSZ) + p) * 128 + oc4 * 4;
    f32x4 a = *(const f32x4*)(pbuf + base);
    f32x4 c = *(const f32x4*)(pbuf + (size_t)(2 * HWSZ * 128) + base);
    half4 t4;
#pragma unroll
    for (int r = 0; r < 4; ++r) {
        float v = (a[r] + c[r]) * (1.0f / 16.0f) + bias[oc4 * 4 + r];
        t4[r] = (_Float16)gelu_f(v);
    }
    if (OUTMODE == 0) {
        int h = p >> 6, w = p & 63;
        _Float16* dst = outH + (size_t)b * 70 * 72 * 128 +
                        ((size_t)(h + 3) * 72 + (3 + w)) * 128 + oc4 * 4;
        *(half4*)dst = t4;
    } else {
        *(half4*)(outH + base) = t4;
    }
}

// ---------------- KZ: z = gelu(a) * g  (CL f16)
__global__ __launch_bounds__(256) void kz_cl(const _Float16* __restrict__ a5cl,
                                             const _Float16* __restrict__ gcl,
                                             _Float16* __restrict__ zbuf) {
    int idx = blockIdx.x * 256 + threadIdx.x;  // half8 index, 131072 total
    half8 a = ((const half8*)a5cl)[idx];
    half8 g = ((const half8*)gcl)[idx];
    half8 z;
#pragma unroll
    for (int j = 0; j < 8; ++j) z[j] = (_Float16)(gelu_f((float)a[j]) * (float)g[j]);
    ((half8*)zbuf)[idx] = z;
}

// ---------------- K6: out(B,HW,32) = z_cl(B,HW,128) @ w2(128,32) + b2
__global__ __launch_bounds__(256) void k6_cl(const _Float16* __restrict__ zbuf,
                                             const float* __restrict__ w2,
                                             const float* __restrict__ b2,
                                             float* __restrict__ out) {
    int idx = blockIdx.x * 256 + threadIdx.x;  // (b,p,d)
    int d = idx & 31;
    int p = (idx >> 5) & 4095;
    int b = idx >> 17;
    const _Float16* zr = zbuf + ((size_t)(b * HWSZ) + p) * 128;
    float acc = b2[d];
#pragma unroll
    for (int c8 = 0; c8 < 16; ++c8) {
        half8 v = *(const half8*)(zr + c8 * 8);
#pragma unroll
        for (int j = 0; j < 8; ++j) acc = fmaf((float)v[j], w2[(c8 * 8 + j) * 32 + d], acc);
    }
    out[idx] = acc;
}

extern "C" void kernel_launch(void* const* d_in, const int* in_sizes, int n_in,
                              void* d_out, int out_size, void* d_ws, size_t ws_size,
                              hipStream_t stream) {
    const float* x   = (const float*)d_in[0];
    const float* w1  = (const float*)d_in[1];
    const float* b1  = (const float*)d_in[2];
    const float* dww = (const float*)d_in[3];
    const float* dwb = (const float*)d_in[4];
    const float* pww = (const float*)d_in[5];
    const float* pwb = (const float*)d_in[6];
    const float* o3w = (const float*)d_in[7];
    const float* o3b = (const float*)d_in[8];
    const float* d3w = (const float*)d_in[9];
    const float* d3b = (const float*)d_in[10];
    const float* o4w = (const float*)d_in[11];
    const float* o4b = (const float*)d_in[12];
    const float* d4w = (const float*)d_in[13];
    const float* d4b = (const float*)d_in[14];
    const float* o5w = (const float*)d_in[15];
    const float* o5b = (const float*)d_in[16];
    const float* d5w = (const float*)d_in[17];
    const float* d5b = (const float*)d_in[18];
    const float* w2  = (const float*)d_in[19];
    const float* b2  = (const float*)d_in[20];

    float* ws = (float*)d_ws;
    float* offb = ws;                              // 1,048,576 f32
    _Float16* clA  = (_Float16*)(ws + 1048576);    // 1,290,240 f16
    _Float16* clB  = (_Float16*)(ws + 1693696);    // 1,290,240 f16
    _Float16* xicl = (_Float16*)(ws + 2338816);    // 1,048,576 f16
    _Float16* dcl  = (_Float16*)(ws + 2863104);    // 1,048,576 f16
    _Float16* gcl  = (_Float16*)(ws + 3387392);    // 1,048,576 f16
    _Float16* a5cl = (_Float16*)(ws + 3911680);    // 1,048,576 f16
    _Float16* zbuf = (_Float16*)(ws + 4435968);    // 1,048,576 f16
    _Float16* wA3  = (_Float16*)(ws + 4960256);    // 49*128*128 f16
    _Float16* wA4  = (_Float16*)(ws + 5361664);    // 9*32*128
    _Float16* wA5  = (_Float16*)(ws + 5380096);    // 25*64*128
    _Float16* wM3  = (_Float16*)(ws + 5482496);    // 49*128*128
    _Float16* wM4  = (_Float16*)(ws + 5883904);    // 9*128*128
    _Float16* wM5  = (_Float16*)(ws + 5957632);    // 25*128*128
    _Float16* dwt  = (_Float16*)(ws + 6162432);    // 9*128
    _Float16* pwt  = (_Float16*)(ws + 6163008);    // 256*128 f16
    float* pbuf    = ws + 6179392;                 // 2 x 1,048,576 f32 partials

    // weight transforms
    dwtk<<<5, 256, 0, stream>>>(dww, dwt);
    pcast<<<128, 256, 0, stream>>>(pww, pwt);
    wtr<<<3136, 256, 0, stream>>>(o3w, wA3, 49, 128, 98, 256.f);
    wtr<<<144,  256, 0, stream>>>(o4w, wA4, 9,  32,  18, 256.f);
    wtr<<<800,  256, 0, stream>>>(o5w, wA5, 25, 64,  50, 256.f);
    wtr<<<3136, 256, 0, stream>>>(d3w, wM3, 49, 128, 128, 16.f);
    wtr<<<576,  256, 0, stream>>>(d4w, wM4, 9,  128, 128, 16.f);
    wtr<<<1600, 256, 0, stream>>>(d5w, wM5, 25, 128, 128, 16.f);
    zcl<<<2520, 256, 0, stream>>>((unsigned int*)clA);
    zcl<<<2520, 256, 0, stream>>>((unsigned int*)clB);

    // front of net
    k1_cl<<<4096, 256, 0, stream>>>(x, w1, b1, xicl);
    k2_cl<<<512, 256, 0, stream>>>(xicl, dwt, dwb, dcl);
    k3G<<<dim3(512, 2), 512, 0, stream>>>(dcl, pwt, pwb, clA, gcl);

    // d3: k=7, pad=3, T=49 (chunks 25/24)
    k4Gv3<7, 3, 49, 8, 1, 2, 32><<<256, 512, 0, stream>>>(clA, wA3, o3b, offb, 98);
    k5Gv6<7, 3, 25, 49><<<dim3(256, 2), 512, 0, stream>>>(clA, offb, 128, wM3, pbuf);
    krd<0><<<1024, 256, 0, stream>>>(pbuf, d3b, clB);

    // d4: k=3, pad=1, T=9 (chunks 5/4)
    k4Gv3<3, 1, 9, 2, 4, 1, 64><<<128, 512, 0, stream>>>(clB, wA4, o4b, offb, 18);
    k5Gv6<3, 1, 5, 9><<<dim3(256, 2), 512, 0, stream>>>(clB, offb, 32, wM4, pbuf);
    krd<0><<<1024, 256, 0, stream>>>(pbuf, d4b, clA);

    // d5: k=5, pad=2, T=25 (chunks 13/12) -> flat CL f16
    k4Gv3<5, 2, 25, 4, 2, 1, 32><<<256, 512, 0, stream>>>(clA, wA5, o5b, offb, 50);
    k5Gv6<5, 2, 13, 25><<<dim3(256, 2), 512, 0, stream>>>(clA, offb, 64, wM5, pbuf);
    krd<2><<<1024, 256, 0, stream>>>(pbuf, d5b, a5cl);

    // tail
    kz_cl<<<512, 256, 0, stream>>>(a5cl, gcl, zbuf);
    k6_cl<<<1024, 256, 0, stream>>>(zbuf, w2, b2, (float*)d_out);
}

// Round 9
// 273.536 us; speedup vs baseline: 1.2795x; 1.0367x over previous
//
#include <hip/hip_runtime.h>
#include <hip/hip_bf16.h>

// Shapes: B=2, H=W=64, HW=4096, DIM=32, HID=128
#define HWSZ 4096

typedef _Float16 half8 __attribute__((ext_vector_type(8)));
typedef _Float16 half4 __attribute__((ext_vector_type(4)));
typedef float f32x4 __attribute__((ext_vector_type(4)));

__device__ __forceinline__ float gelu_f(float v) {
    return 0.5f * v * (1.0f + erff(v * 0.7071067811865475f));
}

// ---------------- KPREP: all weight transforms fused (range ladder)
__device__ __forceinline__ void wtr_elem(const float* __restrict__ w,
                                         _Float16* __restrict__ o,
                                         int i, int T, int Op, int O, float scale) {
    int c = i & 127;
    int op = (i >> 7) % Op;
    int t = i / (128 * Op);
    float v = (op < O) ? w[((size_t)(op * 128 + c)) * T + t] * scale : 0.f;
    o[i] = (_Float16)v;
}

__global__ __launch_bounds__(256) void kprep(const float* __restrict__ dww,
                                             const float* __restrict__ pww,
                                             const float* __restrict__ o3w,
                                             const float* __restrict__ d3w,
                                             const float* __restrict__ o4w,
                                             const float* __restrict__ d4w,
                                             const float* __restrict__ o5w,
                                             const float* __restrict__ d5w,
                                             _Float16* __restrict__ dwt,
                                             _Float16* __restrict__ pwt,
                                             _Float16* __restrict__ wA3,
                                             _Float16* __restrict__ wA4,
                                             _Float16* __restrict__ wA5,
                                             _Float16* __restrict__ wM3,
                                             _Float16* __restrict__ wM4,
                                             _Float16* __restrict__ wM5) {
    int i = blockIdx.x * 256 + threadIdx.x;
    if (i < 1152) {
        int c = i & 127, j = i >> 7;
        dwt[j * 128 + c] = (_Float16)dww[c * 9 + j];
        return;
    }
    i -= 1152;
    if (i < 32768) { pwt[i] = (_Float16)pww[i]; return; }
    i -= 32768;
    if (i < 802816) { wtr_elem(o3w, wA3, i, 49, 128, 98, 256.f); return; }
    i -= 802816;
    if (i < 36864) { wtr_elem(o4w, wA4, i, 9, 32, 18, 256.f); return; }
    i -= 36864;
    if (i < 204800) { wtr_elem(o5w, wA5, i, 25, 64, 50, 256.f); return; }
    i -= 204800;
    if (i < 802816) { wtr_elem(d3w, wM3, i, 49, 128, 128, 16.f); return; }
    i -= 802816;
    if (i < 147456) { wtr_elem(d4w, wM4, i, 9, 128, 128, 16.f); return; }
    i -= 147456;
    if (i < 409600) { wtr_elem(d5w, wM5, i, 25, 128, 128, 16.f); return; }
}

// ---------------- zero channels-last padded buffers (clA+clB contiguous, as uints)
__global__ __launch_bounds__(256) void zcl(unsigned int* __restrict__ p) {
    p[blockIdx.x * 256 + threadIdx.x] = 0u;
}

// ---------------- K1: x(B,HW,32) @ w1(32,128) + b1, gelu -> CL f16 (B,HW,128)
__global__ __launch_bounds__(256) void k1_cl(const float* __restrict__ x,
                                             const float* __restrict__ w1,
                                             const float* __restrict__ b1,
                                             _Float16* __restrict__ xicl) {
    int idx = blockIdx.x * 256 + threadIdx.x;  // (b,p,c)
    int c = idx & 127;
    int p = (idx >> 7) & 4095;
    int b = idx >> 19;
    const float* xr = x + (size_t)(b * HWSZ + p) * 32;
    float acc = b1[c];
#pragma unroll
    for (int k = 0; k < 32; ++k) acc = fmaf(xr[k], w1[k * 128 + c], acc);
    xicl[idx] = (_Float16)gelu_f(acc);
}

// ---------------- K2: depthwise 3x3 (pad 1) + bias, CL f16 in/out
__global__ __launch_bounds__(256) void k2_cl(const _Float16* __restrict__ xicl,
                                             const _Float16* __restrict__ dwt,
                                             const float* __restrict__ dwb,
                                             _Float16* __restrict__ dcl) {
    int idx = blockIdx.x * 256 + threadIdx.x;  // (b,p,cg)
    int cg = idx & 15;
    int p = (idx >> 4) & 4095;
    int b = idx >> 16;
    int h = p >> 6, w = p & 63;
    const _Float16* base = xicl + (size_t)b * HWSZ * 128;
    float acc[8];
#pragma unroll
    for (int j = 0; j < 8; ++j) acc[j] = 0.f;
#pragma unroll
    for (int i = 0; i < 3; ++i) {
        int y = h + i - 1;
        if ((unsigned)y > 63u) continue;
#pragma unroll
        for (int j2 = 0; j2 < 3; ++j2) {
            int xx = w + j2 - 1;
            if ((unsigned)xx > 63u) continue;
            half8 v = *(const half8*)(base + ((size_t)(y * 64 + xx)) * 128 + cg * 8);
            half8 wv8 = *(const half8*)(dwt + (i * 3 + j2) * 128 + cg * 8);
#pragma unroll
            for (int j = 0; j < 8; ++j) acc[j] = fmaf((float)v[j], (float)wv8[j], acc[j]);
        }
    }
    half8 o;
#pragma unroll
    for (int j = 0; j < 8; ++j) o[j] = (_Float16)(acc[j] + dwb[cg * 8 + j]);
    *(half8*)(dcl + ((size_t)(b * HWSZ) + p) * 128 + cg * 8) = o;
}

// ---------------- K3G: pointwise 128->256 MFMA GEMM + bias + gelu
__global__ __launch_bounds__(512) void k3G(const _Float16* __restrict__ dcl,
                                           const _Float16* __restrict__ pwt,
                                           const float* __restrict__ pwb,
                                           _Float16* __restrict__ clA,
                                           _Float16* __restrict__ gcl) {
    int tid = threadIdx.x;
    int wv = tid >> 6;
    int l = tid & 63;
    int col = l & 15, kg = l >> 4;
    int blk = blockIdx.x;
    int hf = blockIdx.y;  // 0:a 1:g
    int b = blk >> 8;
    int px0 = (blk & 255) << 4;
    int p = px0 + col;
    const _Float16* bp = dcl + ((size_t)(b * HWSZ) + p) * 128 + kg * 8;
    int oc0 = hf * 128 + wv * 16;
    const _Float16* ap = pwt + (size_t)(oc0 + col) * 128 + kg * 8;
    f32x4 acc = (f32x4){0.f, 0.f, 0.f, 0.f};
#pragma unroll
    for (int cc = 0; cc < 4; ++cc) {
        half8 bf = *(const half8*)(bp + cc * 32);
        half8 af = *(const half8*)(ap + cc * 32);
        acc = __builtin_amdgcn_mfma_f32_16x16x32_f16(af, bf, acc, 0, 0, 0);
    }
    int h = p >> 6, w = p & 63;
    half4 t4;
#pragma unroll
    for (int r = 0; r < 4; ++r) {
        int oc = oc0 + kg * 4 + r;
        t4[r] = (_Float16)gelu_f(acc[r] + pwb[oc]);
    }
    if (hf == 0) {
        _Float16* dst = clA + (size_t)b * 70 * 72 * 128 +
                        ((size_t)(h + 3) * 72 + (w + 3)) * 128 + wv * 16 + kg * 4;
        *(half4*)dst = t4;
    } else {
        *(half4*)(gcl + ((size_t)(b * HWSZ) + p) * 128 + wv * 16 + kg * 4) = t4;
    }
}

// ---------------- K4Gv3: offset conv = implicit-im2col MFMA GEMM with LDS-staged B
template <int KK, int PAD, int T, int MT, int NG, int NA, int WPX>
__global__ __launch_bounds__(512) void k4Gv3(const _Float16* __restrict__ cl,
                                             const _Float16* __restrict__ wA,
                                             const float* __restrict__ obias,
                                             float* __restrict__ offb, int OC) {
    constexpr int OCp = MT * 16;
    constexpr int COLS = WPX + KK - 1;
    constexpr int NB = 64 / WPX;  // w0 positions per row
    __shared__ _Float16 bS[KK * COLS * 128];

    int tid = threadIdx.x;
    int blk = blockIdx.x;
    int w0 = (blk % NB) * WPX;
    int h = (blk / NB) & 63;
    int b = blk / (NB * 64);
    const _Float16* clb = cl + (size_t)b * 70 * 72 * 128;

    int hh0 = h + (3 - PAD);
    int ww0 = w0 + (3 - PAD);
    for (int g = tid; g < KK * COLS * 16; g += 512) {
        int r = g / (COLS * 16);
        int rest = g - r * (COLS * 16);
        int c = rest >> 4;
        int s = rest & 15;
        half8 v = *(const half8*)(clb + ((size_t)(hh0 + r) * 72 + (ww0 + c)) * 128 + s * 8);
        *(half8*)&bS[((r * COLS + c) * 16 + (s ^ (c & 7))) * 8] = v;
    }

    int wv = tid >> 6;
    int l = tid & 63;
    int col = l & 15, kg = l >> 4;
    int m = wv % MT;
    int ng = wv / MT;

    const _Float16* apbase = wA + ((size_t)(m * 16 + col)) * 128 + kg * 8;
    half8 afv[4];
#pragma unroll
    for (int cc = 0; cc < 4; ++cc) afv[cc] = *(const half8*)(apbase + cc * 32);

    f32x4 acc[NA];
#pragma unroll
    for (int a = 0; a < NA; ++a) acc[a] = (f32x4){0.f, 0.f, 0.f, 0.f};

    __syncthreads();

    for (int t = 0; t < T; ++t) {
        int ky = t / KK, kx = t - ky * KK;
        half8 afn[4];
        if (t + 1 < T) {
            const _Float16* apn = apbase + (size_t)(t + 1) * OCp * 128;
#pragma unroll
            for (int cc = 0; cc < 4; ++cc) afn[cc] = *(const half8*)(apn + cc * 32);
        }
#pragma unroll
        for (int a = 0; a < NA; ++a) {
            int cw = ng * NA * 16 + a * 16 + col + kx;
#pragma unroll
            for (int cc = 0; cc < 4; ++cc) {
                half8 bf = *(const half8*)&bS[((ky * COLS + cw) * 16 + ((cc * 4 + kg) ^ (cw & 7))) * 8];
                acc[a] = __builtin_amdgcn_mfma_f32_16x16x32_f16(afv[cc], bf, acc[a], 0, 0, 0);
            }
        }
#pragma unroll
        for (int cc = 0; cc < 4; ++cc) afv[cc] = afn[cc];
    }

#pragma unroll
    for (int a = 0; a < NA; ++a) {
        int px = h * 64 + w0 + ng * NA * 16 + a * 16 + col;
#pragma unroll
        for (int r = 0; r < 4; ++r) {
            int oc = m * 16 + kg * 4 + r;
            float v = acc[a][r] * (1.0f / 256.0f) + (oc < OC ? obias[oc] : 0.f);
            offb[((size_t)(b * OCp + oc)) * HWSZ + px] = v;
        }
    }
}

// ---------------- K5Gv7: deformable conv, split-T (4 co-resident chunks), f32 partials
// grid (256, NCH): y = tap chunk. Writes raw f32 partials to per-chunk pbuf.
template <int KK, int PAD, int T, int NCH>
__global__ __launch_bounds__(512, 4) void k5Gv7(const _Float16* __restrict__ cl,
                                                const float* __restrict__ offb, int OFFP,
                                                const _Float16* __restrict__ wM,
                                                float* __restrict__ pb0,
                                                float* __restrict__ pb1,
                                                float* __restrict__ pb2,
                                                float* __restrict__ pb3) {
    __shared__ _Float16 panel[2][32][128];  // double-buffered sampled B panel (16 KB)

    int tid = threadIdx.x;
    int blk = blockIdx.x;
    int chunk = blockIdx.y;
    int base = T / NCH, rem = T % NCH;
    int TS = chunk * base + min(chunk, rem);
    int TE = TS + base + (chunk < rem ? 1 : 0);
    int b = blk >> 7;
    int px0 = (blk & 127) << 5;
    const _Float16* clb = cl + (size_t)b * 70 * 72 * 128;
    const float* ob = offb + (size_t)b * OFFP * HWSZ;

    // sampling roles: thread = (pixel, 8-channel slice)
    int px_s = tid >> 4;   // 0..31
    int slice = tid & 15;  // 8 channels
    int p_s = px0 + px_s;
    int h_s = p_s >> 6, w_s = p_s & 63;
    // MFMA roles
    int wv = tid >> 6;
    int l = tid & 63;
    int col = l & 15, kg = l >> 4;

    f32x4 acc0 = (f32x4){0.f, 0.f, 0.f, 0.f};
    f32x4 acc1 = (f32x4){0.f, 0.f, 0.f, 0.f};

    float pwA[4], pwB[4];
    int poA[4], poB[4];
    half8 cA[4], cB[4], wA8[4], wB8[4];

    auto PARAMS = [&](int t, float* pw, int* po) {
        int ky = t / KK, kx = t - ky * KK;
        float dy = ob[(size_t)(2 * t) * HWSZ + p_s];
        float dx = ob[(size_t)(2 * t + 1) * HWSZ + p_s];
        float py = (float)(h_s + ky - PAD) + dy;
        float pxs = (float)(w_s + kx - PAD) + dx;
        float y0f = floorf(py), x0f = floorf(pxs);
        float wy = py - y0f, wx = pxs - x0f;
        int y0 = (int)y0f, x0 = (int)x0f;
        int y1 = y0 + 1, x1 = x0 + 1;
        bool vy0 = (y0 >= 0) && (y0 < 64), vy1 = (y1 >= 0) && (y1 < 64);
        bool vx0 = (x0 >= 0) && (x0 < 64), vx1 = (x1 >= 0) && (x1 < 64);
        int cy0 = min(max(y0, 0), 63) + 3, cy1 = min(max(y1, 0), 63) + 3;
        int cx0 = min(max(x0, 0), 63) + 3, cx1 = min(max(x1, 0), 63) + 3;
        pw[0] = (vy0 && vx0) ? (1.f - wy) * (1.f - wx) : 0.f;
        pw[1] = (vy0 && vx1) ? (1.f - wy) * wx : 0.f;
        pw[2] = (vy1 && vx0) ? wy * (1.f - wx) : 0.f;
        pw[3] = (vy1 && vx1) ? wy * wx : 0.f;
        po[0] = cy0 * 72 * 128; po[1] = cy1 * 72 * 128;
        po[2] = cx0 * 128;      po[3] = cx1 * 128;
    };
    auto LOADC = [&](half8* c, const int* po) {
        const _Float16* s = clb + slice * 8;
        c[0] = *(const half8*)(s + po[0] + po[2]);
        c[1] = *(const half8*)(s + po[0] + po[3]);
        c[2] = *(const half8*)(s + po[1] + po[2]);
        c[3] = *(const half8*)(s + po[1] + po[3]);
    };
    auto BLEND = [&](const half8* c, const float* pw, int buf) {
        half8 r;
#pragma unroll
        for (int j = 0; j < 8; ++j) {
            float v = pw[0] * (float)c[0][j] + pw[1] * (float)c[1][j] +
                      pw[2] * (float)c[2][j] + pw[3] * (float)c[3][j];
            r[j] = (_Float16)v;
        }
        *(half8*)&panel[buf][px_s][(slice ^ (px_s & 7)) * 8] = r;
    };
    auto LOADW = [&](half8* w8, int t) {
        const _Float16* ap = wM + ((size_t)t * 128 + wv * 16 + col) * 128 + kg * 8;
#pragma unroll
        for (int cc = 0; cc < 4; ++cc) w8[cc] = *(const half8*)(ap + cc * 32);
    };
    auto MM = [&](const half8* w8, int buf) {
#pragma unroll
        for (int cc = 0; cc < 4; ++cc) {
            half8 bf0 = *(const half8*)&panel[buf][col][((cc * 4 + kg) ^ (col & 7)) * 8];
            acc0 = __builtin_amdgcn_mfma_f32_16x16x32_f16(w8[cc], bf0, acc0, 0, 0, 0);
            half8 bf1 = *(const half8*)&panel[buf][16 + col][((cc * 4 + kg) ^ (col & 7)) * 8];
            acc1 = __builtin_amdgcn_mfma_f32_16x16x32_f16(w8[cc], bf1, acc1, 0, 0, 0);
        }
    };
    auto BAR = [&]() {
        asm volatile("s_waitcnt lgkmcnt(0)" ::: "memory");
        __builtin_amdgcn_s_barrier();
        __builtin_amdgcn_sched_barrier(0);
    };

    // ---- prologue
    PARAMS(TS, pwA, poA);
    LOADC(cA, poA);
    if (TS + 1 < TE) { PARAMS(TS + 1, pwB, poB); LOADC(cB, poB); }
    LOADW(wA8, TS);
    if (TS + 1 < TE) LOADW(wB8, TS + 1);
    BLEND(cA, pwA, TS & 1);
    if (TS + 2 < TE) { PARAMS(TS + 2, pwA, poA); LOADC(cA, poA); }
    BAR();

    for (int t = TS; t < TE; t += 2) {
        MM(wA8, t & 1);
        if (t + 2 < TE) LOADW(wA8, t + 2);
        if (t + 1 < TE) BLEND(cB, pwB, (t + 1) & 1);
        if (t + 3 < TE) { PARAMS(t + 3, pwB, poB); LOADC(cB, poB); }
        BAR();
        if (t + 1 < TE) {
            MM(wB8, (t + 1) & 1);
            if (t + 3 < TE) LOADW(wB8, t + 3);
            if (t + 2 < TE) BLEND(cA, pwA, (t + 2) & 1);
            if (t + 4 < TE) { PARAMS(t + 4, pwA, poA); LOADC(cA, poA); }
            BAR();
        }
    }

    // ---- epilogue: raw f32 partials
    float* pb = (chunk == 0) ? pb0 : (chunk == 1) ? pb1 : (chunk == 2) ? pb2 : pb3;
#pragma unroll
    for (int n = 0; n < 2; ++n) {
        f32x4 acc = n ? acc1 : acc0;
        int p = px0 + n * 16 + col;
        *(f32x4*)&pb[((size_t)(b * HWSZ) + p) * 128 + wv * 16 + kg * 4] = acc;
    }
}

// ---------------- KRD4: reduce 4 partials + bias + gelu -> f16 CL (padded or flat)
template <int OUTMODE>
__global__ __launch_bounds__(256) void krd4(const float* __restrict__ p0,
                                            const float* __restrict__ p1,
                                            const float* __restrict__ p2,
                                            const float* __restrict__ p3,
                                            const float* __restrict__ bias,
                                            _Float16* __restrict__ outH) {
    int idx = blockIdx.x * 256 + threadIdx.x;  // 262144: (b,p,oc4)
    int oc4 = idx & 31;
    int p = (idx >> 5) & 4095;
    int b = idx >> 17;
    size_t base = ((size_t)(b * HWSZ) + p) * 128 + oc4 * 4;
    f32x4 a = *(const f32x4*)(p0 + base);
    f32x4 c = *(const f32x4*)(p1 + base);
    f32x4 d = *(const f32x4*)(p2 + base);
    f32x4 e = *(const f32x4*)(p3 + base);
    half4 t4;
#pragma unroll
    for (int r = 0; r < 4; ++r) {
        float v = ((a[r] + c[r]) + (d[r] + e[r])) * (1.0f / 16.0f) + bias[oc4 * 4 + r];
        t4[r] = (_Float16)gelu_f(v);
    }
    if (OUTMODE == 0) {
        int h = p >> 6, w = p & 63;
        _Float16* dst = outH + (size_t)b * 70 * 72 * 128 +
                        ((size_t)(h + 3) * 72 + (3 + w)) * 128 + oc4 * 4;
        *(half4*)dst = t4;
    } else {
        *(half4*)(outH + base) = t4;
    }
}

// ---------------- K6Z: z = gelu(a)*g fused with out = z @ w2 + b2
__global__ __launch_bounds__(256) void k6z(const _Float16* __restrict__ a5cl,
                                           const _Float16* __restrict__ gcl,
                                           const float* __restrict__ w2,
                                           const float* __restrict__ b2,
                                           float* __restrict__ out) {
    __shared__ float zs[16][128];
    int tid = threadIdx.x;
    int blk = blockIdx.x;  // 512: (b, 16-px group)
    int b = blk >> 8;
    int px0 = (blk & 255) << 4;
    int px = tid >> 4, sl = tid & 15;
    size_t rb = ((size_t)(b * HWSZ) + px0 + px) * 128 + sl * 8;
    half8 a = *(const half8*)(a5cl + rb);
    half8 g = *(const half8*)(gcl + rb);
#pragma unroll
    for (int j = 0; j < 8; ++j)
        zs[px][sl * 8 + j] = gelu_f((float)a[j]) * (float)g[j];
    __syncthreads();
    int d2 = (tid & 15) * 2;
    float acc0 = b2[d2], acc1 = b2[d2 + 1];
#pragma unroll 16
    for (int c = 0; c < 128; ++c) {
        float zv = zs[px][c];
        acc0 = fmaf(zv, w2[c * 32 + d2], acc0);
        acc1 = fmaf(zv, w2[c * 32 + d2 + 1], acc1);
    }
    float* o = out + ((size_t)(b * HWSZ) + px0 + px) * 32 + d2;
    o[0] = acc0;
    o[1] = acc1;
}

extern "C" void kernel_launch(void* const* d_in, const int* in_sizes, int n_in,
                              void* d_out, int out_size, void* d_ws, size_t ws_size,
                              hipStream_t stream) {
    const float* x   = (const float*)d_in[0];
    const float* w1  = (const float*)d_in[1];
    const float* b1  = (const float*)d_in[2];
    const float* dww = (const float*)d_in[3];
    const float* dwb = (const float*)d_in[4];
    const float* pww = (const float*)d_in[5];
    const float* pwb = (const float*)d_in[6];
    const float* o3w = (const float*)d_in[7];
    const float* o3b = (const float*)d_in[8];
    const float* d3w = (const float*)d_in[9];
    const float* d3b = (const float*)d_in[10];
    const float* o4w = (const float*)d_in[11];
    const float* o4b = (const float*)d_in[12];
    const float* d4w = (const float*)d_in[13];
    const float* d4b = (const float*)d_in[14];
    const float* o5w = (const float*)d_in[15];
    const float* o5b = (const float*)d_in[16];
    const float* d5w = (const float*)d_in[17];
    const float* d5b = (const float*)d_in[18];
    const float* w2  = (const float*)d_in[19];
    const float* b2  = (const float*)d_in[20];

    float* ws = (float*)d_ws;
    float* offb = ws;                              // 0 .. 1,048,576
    _Float16* clA  = (_Float16*)(ws + 1048576);    // 1,290,240 f16
    _Float16* clB  = (_Float16*)(ws + 1693696);    // 1,290,240 f16
    _Float16* xicl = (_Float16*)(ws + 2338816);    // 524,288 floats worth (dead after k3G)
    _Float16* dcl  = (_Float16*)(ws + 2863104);    // 524,288 floats worth (dead after k3G)
    _Float16* gcl  = (_Float16*)(ws + 3387392);    // 524,288 floats
    _Float16* a5cl = (_Float16*)(ws + 3911680);    // 524,288 floats
    _Float16* wA3  = (_Float16*)(ws + 4960256);    // 49*128*128 f16
    _Float16* wA4  = (_Float16*)(ws + 5361664);
    _Float16* wA5  = (_Float16*)(ws + 5380096);
    _Float16* wM3  = (_Float16*)(ws + 5482496);
    _Float16* wM4  = (_Float16*)(ws + 5883904);
    _Float16* wM5  = (_Float16*)(ws + 5957632);
    _Float16* dwt  = (_Float16*)(ws + 6162432);
    _Float16* pwt  = (_Float16*)(ws + 6163008);
    float* pb0 = ws + 6179392;                     // 1,048,576 f32
    float* pb1 = ws + 7227968;                     // 1,048,576 f32
    float* pb2 = ws + 2338816;                     // aliases xicl+dcl (dead after k3G)
    float* pb3 = ws + 8276544;                     // 1,048,576 f32 (ends 9,325,120 < proven 9.78M)

    // prep (2 launches)
    kprep<<<9525, 256, 0, stream>>>(dww, pww, o3w, d3w, o4w, d4w, o5w, d5w,
                                    dwt, pwt, wA3, wA4, wA5, wM3, wM4, wM5);
    zcl<<<5040, 256, 0, stream>>>((unsigned int*)clA);  // clA+clB contiguous

    // front of net
    k1_cl<<<4096, 256, 0, stream>>>(x, w1, b1, xicl);
    k2_cl<<<512, 256, 0, stream>>>(xicl, dwt, dwb, dcl);
    k3G<<<dim3(512, 2), 512, 0, stream>>>(dcl, pwt, pwb, clA, gcl);

    // d3: k=7, pad=3, T=49 (chunks 13/12/12/12)
    k4Gv3<7, 3, 49, 8, 1, 2, 32><<<256, 512, 0, stream>>>(clA, wA3, o3b, offb, 98);
    k5Gv7<7, 3, 49, 4><<<dim3(256, 4), 512, 0, stream>>>(clA, offb, 128, wM3, pb0, pb1, pb2, pb3);
    krd4<0><<<1024, 256, 0, stream>>>(pb0, pb1, pb2, pb3, d3b, clB);

    // d4: k=3, pad=1, T=9 (chunks 3/2/2/2)
    k4Gv3<3, 1, 9, 2, 4, 1, 64><<<128, 512, 0, stream>>>(clB, wA4, o4b, offb, 18);
    k5Gv7<3, 1, 9, 4><<<dim3(256, 4), 512, 0, stream>>>(clB, offb, 32, wM4, pb0, pb1, pb2, pb3);
    krd4<0><<<1024, 256, 0, stream>>>(pb0, pb1, pb2, pb3, d4b, clA);

    // d5: k=5, pad=2, T=25 (chunks 7/6/6/6) -> flat CL f16
    k4Gv3<5, 2, 25, 4, 2, 1, 32><<<256, 512, 0, stream>>>(clA, wA5, o5b, offb, 50);
    k5Gv7<5, 2, 25, 4><<<dim3(256, 4), 512, 0, stream>>>(clA, offb, 64, wM5, pb0, pb1, pb2, pb3);
    krd4<2><<<1024, 256, 0, stream>>>(pb0, pb1, pb2, pb3, d5b, a5cl);

    // tail (fused)
    k6z<<<512, 256, 0, stream>>>(a5cl, gcl, w2, b2, (float*)d_out);
}